// Round 2
// baseline (467.927 us; speedup 1.0000x reference)
//
#include <hip/hip_runtime.h>

// SSIM, wave-per-row-strip, branch-free + software-pipelined.
// Each wave owns full image width: 64 lanes x 8 cols = 512. Vertical 11-row
// box sums slide in registers; retiring row re-loaded from global (L2/L3-hot).
// Horizontal 11-col window via __shfl halo exchange (no LDS, no barriers).
// R5: occupancy fix. rocprof showed VALUBusy 30% / HBM 33% / Occ 17% -> pure
// concurrency starvation at 2 waves/SIMD (grid-limited). RS 16->8 doubles the
// grid to 4096 waves = 4/SIMD (the max at VGPR<=128); __launch_bounds__(256,4)
// pins it. Bijective XCD swizzle keeps adjacent strips (which share the 10-row
// vertical halo) on the same XCD L2 to damp the extra halo fetch (2.25x raw
// row amplification vs 1.63x at RS=16).
// (R5 resubmit — previous run died on GPUAcquisitionTimeout, no counters.)

static constexpr int HI = 512, WI = 512;
static constexpr int RS = 8;              // output rows per wave-strip
static constexpr int STEPS = RS + 10;     // 18
static constexpr int SPB = HI / RS;       // strips per batch = 64

struct R8 { float4 a, b; };

__device__ __forceinline__ R8 ld8(const float* p) {
  R8 r; r.a = ((const float4*)p)[0]; r.b = ((const float4*)p)[1]; return r;
}

__device__ __forceinline__ void horiz11(const float v[8], float H[8], int lane) {
  float L[5], R[5];
#pragma unroll
  for (int k = 0; k < 5; ++k) {
    float lt = __shfl(v[3 + k], (lane + 63) & 63);
    L[k] = (lane == 0) ? 0.f : lt;      // image cols -5..-1 are zero-pad
    float rt = __shfl(v[k], (lane + 1) & 63);
    R[k] = (lane == 63) ? 0.f : rt;     // image cols 512..516 are zero-pad
  }
  float h = (((L[0] + L[1]) + (L[2] + L[3])) + ((L[4] + v[0]) + (v[1] + v[2])))
            + ((v[3] + v[4]) + v[5]);
  H[0] = h;
  h = h - L[0] + v[6]; H[1] = h;
  h = h - L[1] + v[7]; H[2] = h;
  h = h - L[2] + R[0]; H[3] = h;
  h = h - L[3] + R[1]; H[4] = h;
  h = h - L[4] + R[2]; H[5] = h;
  h = h - v[0] + R[3]; H[6] = h;
  h = h - v[1] + R[4]; H[7] = h;
}

__global__ __launch_bounds__(256, 4)
void ssim_wave(const float* __restrict__ img, const float* __restrict__ ref,
               const float* __restrict__ drng, const float* __restrict__ zrow,
               float* __restrict__ out)
{
  // Bijective XCD swizzle: XCD k gets a contiguous chunk of strips so that
  // adjacent strips (sharing 10 halo rows) hit the same per-XCD L2.
  int bid = (int)blockIdx.x;
  const int nb = (int)gridDim.x;
  if ((nb & 7) == 0) {
    const int cpx = nb >> 3;
    bid = (bid & 7) * cpx + (bid >> 3);
  }

  const int lane = threadIdx.x & 63;
  const int wv   = bid * 4 + (threadIdx.x >> 6);
  const int b    = wv / SPB;
  const int r0   = (wv % SPB) * RS;
  const int c0   = lane * 8;

  const float dr  = drng[b];
  const float C1  = (0.01f * dr) * (0.01f * dr);
  const float C2  = (0.03f * dr) * (0.03f * dr);
  const float inv_n    = 1.0f / 121.0f;
  const float cov_norm = 121.0f / 120.0f;

  const size_t base = (size_t)b * ((size_t)HI * WI);
  const float* xb = img + base;
  const float* yb = ref + base;
  float*       ob = out + base;

  // wave-uniform pointer selects; OOB -> dummy zero row (branch-free loads)
  auto nptr = [&](const float* tb, int i) -> const float* {
    const int ri = r0 - 5 + i;
    return (((unsigned)ri < (unsigned)HI) ? tb + (size_t)ri * WI : zrow) + c0;
  };
  auto optr = [&](const float* tb, int i) -> const float* {
    const int ro = r0 - 16 + i;                  // = ri - 11
    return ((i >= 11 && ro >= 0) ? tb + (size_t)ro * WI : zrow) + c0;
  };

  float Sx[8], Sy[8], Sxx[8], Syy[8], Sxy[8];
#pragma unroll
  for (int c = 0; c < 8; ++c) { Sx[c]=0.f; Sy[c]=0.f; Sxx[c]=0.f; Syy[c]=0.f; Sxy[c]=0.f; }

  // depth-2 pipeline: slot[i&1] holds step i's 4 row-octets
  R8 nx[2], ny[2], ox[2], oy[2];
  nx[0]=ld8(nptr(xb,0)); ny[0]=ld8(nptr(yb,0)); ox[0]=ld8(optr(xb,0)); oy[0]=ld8(optr(yb,0));
  nx[1]=ld8(nptr(xb,1)); ny[1]=ld8(nptr(yb,1)); ox[1]=ld8(optr(xb,1)); oy[1]=ld8(optr(yb,1));

#pragma unroll 2
  for (int i = 0; i < STEPS; ++i) {
    const int s = i & 1;
    // consume current slot into locals
    float xn[8] = { nx[s].a.x, nx[s].a.y, nx[s].a.z, nx[s].a.w,
                    nx[s].b.x, nx[s].b.y, nx[s].b.z, nx[s].b.w };
    float yn[8] = { ny[s].a.x, ny[s].a.y, ny[s].a.z, ny[s].a.w,
                    ny[s].b.x, ny[s].b.y, ny[s].b.z, ny[s].b.w };
    float xo[8] = { ox[s].a.x, ox[s].a.y, ox[s].a.z, ox[s].a.w,
                    ox[s].b.x, ox[s].b.y, ox[s].b.z, ox[s].b.w };
    float yo[8] = { oy[s].a.x, oy[s].a.y, oy[s].a.z, oy[s].a.w,
                    oy[s].b.x, oy[s].b.y, oy[s].b.z, oy[s].b.w };

    // refill slot with step i+2 (issued now, consumed 2 bodies later)
    if (i + 2 < STEPS) {
      nx[s]=ld8(nptr(xb,i+2)); ny[s]=ld8(nptr(yb,i+2));
      ox[s]=ld8(optr(xb,i+2)); oy[s]=ld8(optr(yb,i+2));
    }

#pragma unroll
    for (int c = 0; c < 8; ++c) {
      Sx[c]  += xn[c] - xo[c];
      Sy[c]  += yn[c] - yo[c];
      Sxx[c] = fmaf(xn[c], xn[c], fmaf(-xo[c], xo[c], Sxx[c]));
      Syy[c] = fmaf(yn[c], yn[c], fmaf(-yo[c], yo[c], Syy[c]));
      Sxy[c] = fmaf(xn[c], yn[c], fmaf(-xo[c], yo[c], Sxy[c]));
    }

    if (i >= 10) {
      float H0[8], H1[8], H2[8], H3[8], H4[8];
      horiz11(Sx,  H0, lane);
      horiz11(Sy,  H1, lane);
      horiz11(Sxx, H2, lane);
      horiz11(Syy, H3, lane);
      horiz11(Sxy, H4, lane);

      float res[8];
#pragma unroll
      for (int c = 0; c < 8; ++c) {
        const float ux  = H0[c] * inv_n, uy  = H1[c] * inv_n;
        const float uxx = H2[c] * inv_n, uyy = H3[c] * inv_n, uxy = H4[c] * inv_n;
        const float vx  = cov_norm * (uxx - ux * ux);
        const float vy  = cov_norm * (uyy - uy * uy);
        const float vxy = cov_norm * (uxy - ux * uy);
        const float A1 = 2.f * ux * uy + C1;
        const float A2 = 2.f * vxy + C2;
        const float B1 = ux * ux + uy * uy + C1;
        const float B2 = vx + vy + C2;
        res[c] = (A1 * A2) * __builtin_amdgcn_rcpf(B1 * B2);
      }
      const int ro = r0 + i - 10;
      float4* po = (float4*)(ob + (size_t)ro * WI + c0);
      po[0] = make_float4(res[0], res[1], res[2], res[3]);
      po[1] = make_float4(res[4], res[5], res[6], res[7]);
    }
  }
}

extern "C" void kernel_launch(void* const* d_in, const int* in_sizes, int n_in,
                              void* d_out, int out_size, void* d_ws, size_t ws_size,
                              hipStream_t stream)
{
  const float* img = (const float*)d_in[0];
  const float* ref = (const float*)d_in[1];
  const float* drg = (const float*)d_in[2];
  float* out = (float*)d_out;

  // zero dummy row (d_ws is re-poisoned to 0xAA before every launch)
  hipMemsetAsync(d_ws, 0, (size_t)WI * sizeof(float) + 64, stream);

  const int B = in_sizes[0] / (HI * WI);          // 64
  const int waves = B * SPB;                      // 4096
  dim3 grid(waves / 4);                           // 1024 blocks, 4 waves each
  dim3 block(256);
  hipLaunchKernelGGL(ssim_wave, grid, block, 0, stream,
                     img, ref, drg, (const float*)d_ws, out);
}

// Round 3
// 222.561 us; speedup vs baseline: 2.1025x; 2.1025x over previous
//
#include <hip/hip_runtime.h>

// SSIM, wave-per-row-strip, branch-free + software-pipelined.
// Each wave owns full image width: 64 lanes x 8 cols = 512. Vertical 11-row
// box sums slide in registers; retiring row re-loaded from global (L2/L3-hot).
// Horizontal 11-col window via __shfl halo exchange (no LDS, no barriers).
// R6: RS=8 grid doubling kept (4096 waves = 16/CU offered), XCD swizzle kept,
// but launch_bounds reverted to (256,2). R5's (256,4) floor made the allocator
// clamp to 64 VGPR (granule rounding) -> ~40 live floats spilled to scratch:
// WRITE_SIZE 65->711 MB, dur 90->350us. At the natural 108 VGPR (<=128),
// hardware already residences 4 waves/SIMD -- no floor needed, the grid size
// was the only real limiter.

static constexpr int HI = 512, WI = 512;
static constexpr int RS = 8;              // output rows per wave-strip
static constexpr int STEPS = RS + 10;     // 18
static constexpr int SPB = HI / RS;       // strips per batch = 64

struct R8 { float4 a, b; };

__device__ __forceinline__ R8 ld8(const float* p) {
  R8 r; r.a = ((const float4*)p)[0]; r.b = ((const float4*)p)[1]; return r;
}

__device__ __forceinline__ void horiz11(const float v[8], float H[8], int lane) {
  float L[5], R[5];
#pragma unroll
  for (int k = 0; k < 5; ++k) {
    float lt = __shfl(v[3 + k], (lane + 63) & 63);
    L[k] = (lane == 0) ? 0.f : lt;      // image cols -5..-1 are zero-pad
    float rt = __shfl(v[k], (lane + 1) & 63);
    R[k] = (lane == 63) ? 0.f : rt;     // image cols 512..516 are zero-pad
  }
  float h = (((L[0] + L[1]) + (L[2] + L[3])) + ((L[4] + v[0]) + (v[1] + v[2])))
            + ((v[3] + v[4]) + v[5]);
  H[0] = h;
  h = h - L[0] + v[6]; H[1] = h;
  h = h - L[1] + v[7]; H[2] = h;
  h = h - L[2] + R[0]; H[3] = h;
  h = h - L[3] + R[1]; H[4] = h;
  h = h - L[4] + R[2]; H[5] = h;
  h = h - v[0] + R[3]; H[6] = h;
  h = h - v[1] + R[4]; H[7] = h;
}

__global__ __launch_bounds__(256, 2)
void ssim_wave(const float* __restrict__ img, const float* __restrict__ ref,
               const float* __restrict__ drng, const float* __restrict__ zrow,
               float* __restrict__ out)
{
  // Bijective XCD swizzle: XCD k gets a contiguous chunk of strips so that
  // adjacent strips (sharing 10 halo rows) hit the same per-XCD L2.
  int bid = (int)blockIdx.x;
  const int nb = (int)gridDim.x;
  if ((nb & 7) == 0) {
    const int cpx = nb >> 3;
    bid = (bid & 7) * cpx + (bid >> 3);
  }

  const int lane = threadIdx.x & 63;
  const int wv   = bid * 4 + (threadIdx.x >> 6);
  const int b    = wv / SPB;
  const int r0   = (wv % SPB) * RS;
  const int c0   = lane * 8;

  const float dr  = drng[b];
  const float C1  = (0.01f * dr) * (0.01f * dr);
  const float C2  = (0.03f * dr) * (0.03f * dr);
  const float inv_n    = 1.0f / 121.0f;
  const float cov_norm = 121.0f / 120.0f;

  const size_t base = (size_t)b * ((size_t)HI * WI);
  const float* xb = img + base;
  const float* yb = ref + base;
  float*       ob = out + base;

  // wave-uniform pointer selects; OOB -> dummy zero row (branch-free loads)
  auto nptr = [&](const float* tb, int i) -> const float* {
    const int ri = r0 - 5 + i;
    return (((unsigned)ri < (unsigned)HI) ? tb + (size_t)ri * WI : zrow) + c0;
  };
  auto optr = [&](const float* tb, int i) -> const float* {
    const int ro = r0 - 16 + i;                  // = ri - 11
    return ((i >= 11 && ro >= 0) ? tb + (size_t)ro * WI : zrow) + c0;
  };

  float Sx[8], Sy[8], Sxx[8], Syy[8], Sxy[8];
#pragma unroll
  for (int c = 0; c < 8; ++c) { Sx[c]=0.f; Sy[c]=0.f; Sxx[c]=0.f; Syy[c]=0.f; Sxy[c]=0.f; }

  // depth-2 pipeline: slot[i&1] holds step i's 4 row-octets
  R8 nx[2], ny[2], ox[2], oy[2];
  nx[0]=ld8(nptr(xb,0)); ny[0]=ld8(nptr(yb,0)); ox[0]=ld8(optr(xb,0)); oy[0]=ld8(optr(yb,0));
  nx[1]=ld8(nptr(xb,1)); ny[1]=ld8(nptr(yb,1)); ox[1]=ld8(optr(xb,1)); oy[1]=ld8(optr(yb,1));

#pragma unroll 2
  for (int i = 0; i < STEPS; ++i) {
    const int s = i & 1;
    // consume current slot into locals
    float xn[8] = { nx[s].a.x, nx[s].a.y, nx[s].a.z, nx[s].a.w,
                    nx[s].b.x, nx[s].b.y, nx[s].b.z, nx[s].b.w };
    float yn[8] = { ny[s].a.x, ny[s].a.y, ny[s].a.z, ny[s].a.w,
                    ny[s].b.x, ny[s].b.y, ny[s].b.z, ny[s].b.w };
    float xo[8] = { ox[s].a.x, ox[s].a.y, ox[s].a.z, ox[s].a.w,
                    ox[s].b.x, ox[s].b.y, ox[s].b.z, ox[s].b.w };
    float yo[8] = { oy[s].a.x, oy[s].a.y, oy[s].a.z, oy[s].a.w,
                    oy[s].b.x, oy[s].b.y, oy[s].b.z, oy[s].b.w };

    // refill slot with step i+2 (issued now, consumed 2 bodies later)
    if (i + 2 < STEPS) {
      nx[s]=ld8(nptr(xb,i+2)); ny[s]=ld8(nptr(yb,i+2));
      ox[s]=ld8(optr(xb,i+2)); oy[s]=ld8(optr(yb,i+2));
    }

#pragma unroll
    for (int c = 0; c < 8; ++c) {
      Sx[c]  += xn[c] - xo[c];
      Sy[c]  += yn[c] - yo[c];
      Sxx[c] = fmaf(xn[c], xn[c], fmaf(-xo[c], xo[c], Sxx[c]));
      Syy[c] = fmaf(yn[c], yn[c], fmaf(-yo[c], yo[c], Syy[c]));
      Sxy[c] = fmaf(xn[c], yn[c], fmaf(-xo[c], yo[c], Sxy[c]));
    }

    if (i >= 10) {
      float H0[8], H1[8], H2[8], H3[8], H4[8];
      horiz11(Sx,  H0, lane);
      horiz11(Sy,  H1, lane);
      horiz11(Sxx, H2, lane);
      horiz11(Syy, H3, lane);
      horiz11(Sxy, H4, lane);

      float res[8];
#pragma unroll
      for (int c = 0; c < 8; ++c) {
        const float ux  = H0[c] * inv_n, uy  = H1[c] * inv_n;
        const float uxx = H2[c] * inv_n, uyy = H3[c] * inv_n, uxy = H4[c] * inv_n;
        const float vx  = cov_norm * (uxx - ux * ux);
        const float vy  = cov_norm * (uyy - uy * uy);
        const float vxy = cov_norm * (uxy - ux * uy);
        const float A1 = 2.f * ux * uy + C1;
        const float A2 = 2.f * vxy + C2;
        const float B1 = ux * ux + uy * uy + C1;
        const float B2 = vx + vy + C2;
        res[c] = (A1 * A2) * __builtin_amdgcn_rcpf(B1 * B2);
      }
      const int ro = r0 + i - 10;
      float4* po = (float4*)(ob + (size_t)ro * WI + c0);
      po[0] = make_float4(res[0], res[1], res[2], res[3]);
      po[1] = make_float4(res[4], res[5], res[6], res[7]);
    }
  }
}

extern "C" void kernel_launch(void* const* d_in, const int* in_sizes, int n_in,
                              void* d_out, int out_size, void* d_ws, size_t ws_size,
                              hipStream_t stream)
{
  const float* img = (const float*)d_in[0];
  const float* ref = (const float*)d_in[1];
  const float* drg = (const float*)d_in[2];
  float* out = (float*)d_out;

  // zero dummy row (d_ws is re-poisoned to 0xAA before every launch)
  hipMemsetAsync(d_ws, 0, (size_t)WI * sizeof(float) + 64, stream);

  const int B = in_sizes[0] / (HI * WI);          // 64
  const int waves = B * SPB;                      // 4096
  dim3 grid(waves / 4);                           // 1024 blocks, 4 waves each
  dim3 block(256);
  hipLaunchKernelGGL(ssim_wave, grid, block, 0, stream,
                     img, ref, drg, (const float*)d_ws, out);
}

// Round 4
// 205.764 us; speedup vs baseline: 2.2741x; 1.0816x over previous
//
#include <hip/hip_runtime.h>

// SSIM, wave-per-row-strip, software-pipelined, phase-split.
// Each wave owns full image width: 64 lanes x 8 cols = 512. Vertical 11-row
// box sums slide in registers; retiring row re-loaded from global (L2-hot).
// Horizontal 11-col window via __shfl halo exchange (no LDS, no barriers).
// R7: residency is pinned at 2 waves/SIMD by the VGPR file (compiler budget
// is 256/waves-per-EU: (256,4) clamped to 64 VGPR in R5; 108 VGPR -> 2/SIMD;
// R6's 2x grid moved nothing). At fixed residency, cut dead work: the old
// (retiring-row) streams are structurally zero for t<11, so the warm-up
// phase (t=0..8) loads only the new streams and does add-only accumulation;
// transition steps t=9,10 peeled; steady phase t=11..25 does the full
// add+subtract. ld8s/wave 104->72, VALU/step -25%, zrow traffic gone.
// RS back to 16 (R4's 90us baseline => clean attribution).

static constexpr int HI = 512, WI = 512;
static constexpr int RS = 16;             // output rows per wave-strip
static constexpr int SPB = HI / RS;       // strips per batch = 32

struct R8 { float4 a, b; };

__device__ __forceinline__ R8 ld8(const float* p) {
  R8 r; r.a = ((const float4*)p)[0]; r.b = ((const float4*)p)[1]; return r;
}

__device__ __forceinline__ void unp(const R8& v, float o[8]) {
  o[0]=v.a.x; o[1]=v.a.y; o[2]=v.a.z; o[3]=v.a.w;
  o[4]=v.b.x; o[5]=v.b.y; o[6]=v.b.z; o[7]=v.b.w;
}

__device__ __forceinline__ void horiz11(const float v[8], float H[8], int lane) {
  float L[5], R[5];
#pragma unroll
  for (int k = 0; k < 5; ++k) {
    float lt = __shfl(v[3 + k], (lane + 63) & 63);
    L[k] = (lane == 0) ? 0.f : lt;      // image cols -5..-1 are zero-pad
    float rt = __shfl(v[k], (lane + 1) & 63);
    R[k] = (lane == 63) ? 0.f : rt;     // image cols 512..516 are zero-pad
  }
  float h = (((L[0] + L[1]) + (L[2] + L[3])) + ((L[4] + v[0]) + (v[1] + v[2])))
            + ((v[3] + v[4]) + v[5]);
  H[0] = h;
  h = h - L[0] + v[6]; H[1] = h;
  h = h - L[1] + v[7]; H[2] = h;
  h = h - L[2] + R[0]; H[3] = h;
  h = h - L[3] + R[1]; H[4] = h;
  h = h - L[4] + R[2]; H[5] = h;
  h = h - v[0] + R[3]; H[6] = h;
  h = h - v[1] + R[4]; H[7] = h;
}

__global__ __launch_bounds__(256, 2)
void ssim_wave(const float* __restrict__ img, const float* __restrict__ ref,
               const float* __restrict__ drng, const float* __restrict__ zrow,
               float* __restrict__ out)
{
  // Bijective XCD swizzle (512 blocks % 8 == 0): adjacent strips share 10
  // halo rows -> keep them on the same per-XCD L2.
  int bid = (int)blockIdx.x;
  const int nb = (int)gridDim.x;
  if ((nb & 7) == 0) {
    const int cpx = nb >> 3;
    bid = (bid & 7) * cpx + (bid >> 3);
  }

  const int lane = threadIdx.x & 63;
  const int wv   = bid * 4 + (threadIdx.x >> 6);
  const int b    = wv / SPB;
  const int r0   = (wv % SPB) * RS;
  const int c0   = lane * 8;

  const float dr  = drng[b];
  const float C1  = (0.01f * dr) * (0.01f * dr);
  const float C2  = (0.03f * dr) * (0.03f * dr);
  const float inv_n    = 1.0f / 121.0f;
  const float cov_norm = 121.0f / 120.0f;

  const size_t base = (size_t)b * ((size_t)HI * WI);
  const float* xb = img + base;
  const float* yb = ref + base;
  float*       ob = out + base;

  // wave-uniform pointer selects; OOB -> dummy zero row (branch-free loads)
  auto nrow = [&](const float* tb, int t) -> const float* {
    const int r = r0 - 5 + t;
    return (((unsigned)r < (unsigned)HI) ? tb + (size_t)r * WI : zrow) + c0;
  };
  auto orow = [&](const float* tb, int t) -> const float* {   // only t>=11
    const int r = r0 - 16 + t;
    return (((unsigned)r < (unsigned)HI) ? tb + (size_t)r * WI : zrow) + c0;
  };

  float Sx[8], Sy[8], Sxx[8], Syy[8], Sxy[8];
#pragma unroll
  for (int c = 0; c < 8; ++c) { Sx[c]=0.f; Sy[c]=0.f; Sxx[c]=0.f; Syy[c]=0.f; Sxy[c]=0.f; }

  auto accA = [&](const float xn[8], const float yn[8]) {
#pragma unroll
    for (int c = 0; c < 8; ++c) {
      Sx[c] += xn[c];  Sy[c] += yn[c];
      Sxx[c] = fmaf(xn[c], xn[c], Sxx[c]);
      Syy[c] = fmaf(yn[c], yn[c], Syy[c]);
      Sxy[c] = fmaf(xn[c], yn[c], Sxy[c]);
    }
  };
  auto accB = [&](const float xn[8], const float yn[8],
                  const float xo[8], const float yo[8]) {
#pragma unroll
    for (int c = 0; c < 8; ++c) {
      Sx[c] += xn[c] - xo[c];
      Sy[c] += yn[c] - yo[c];
      Sxx[c] = fmaf(xn[c], xn[c], fmaf(-xo[c], xo[c], Sxx[c]));
      Syy[c] = fmaf(yn[c], yn[c], fmaf(-yo[c], yo[c], Syy[c]));
      Sxy[c] = fmaf(xn[c], yn[c], fmaf(-xo[c], yo[c], Sxy[c]));
    }
  };

  auto emit = [&](int t) {   // output row r0 + t - 10
    float H0[8], H1[8], H2[8], H3[8], H4[8];
    horiz11(Sx,  H0, lane);
    horiz11(Sy,  H1, lane);
    horiz11(Sxx, H2, lane);
    horiz11(Syy, H3, lane);
    horiz11(Sxy, H4, lane);
    float res[8];
#pragma unroll
    for (int c = 0; c < 8; ++c) {
      const float ux  = H0[c] * inv_n, uy  = H1[c] * inv_n;
      const float uxx = H2[c] * inv_n, uyy = H3[c] * inv_n, uxy = H4[c] * inv_n;
      const float vx  = cov_norm * (uxx - ux * ux);
      const float vy  = cov_norm * (uyy - uy * uy);
      const float vxy = cov_norm * (uxy - ux * uy);
      const float A1 = 2.f * ux * uy + C1;
      const float A2 = 2.f * vxy + C2;
      const float B1 = ux * ux + uy * uy + C1;
      const float B2 = vx + vy + C2;
      res[c] = (A1 * A2) * __builtin_amdgcn_rcpf(B1 * B2);
    }
    const int ro = r0 + t - 10;
    float4* po = (float4*)(ob + (size_t)ro * WI + c0);
    po[0] = make_float4(res[0], res[1], res[2], res[3]);
    po[1] = make_float4(res[4], res[5], res[6], res[7]);
  };

  // depth-2 pipeline slots; slot parity = t & 1 (compile-time per body below)
  R8 nx[2], ny[2], ox[2], oy[2];
  nx[0] = ld8(nrow(xb, 0)); ny[0] = ld8(nrow(yb, 0));
  nx[1] = ld8(nrow(xb, 1)); ny[1] = ld8(nrow(yb, 1));

  // ---- Phase A: t = 0..8 — new streams only, add-only accumulate ----
#pragma unroll 2
  for (int t = 0; t < 9; ++t) {
    const int s = t & 1;
    float xn[8], yn[8];
    unp(nx[s], xn); unp(ny[s], yn);
    nx[s] = ld8(nrow(xb, t + 2)); ny[s] = ld8(nrow(yb, t + 2));
    accA(xn, yn);
  }
  // ---- t = 9: start old-stream pipeline (for t=11) ----
  {
    float xn[8], yn[8];
    unp(nx[1], xn); unp(ny[1], yn);
    nx[1] = ld8(nrow(xb, 11)); ny[1] = ld8(nrow(yb, 11));
    ox[1] = ld8(orow(xb, 11)); oy[1] = ld8(orow(yb, 11));
    accA(xn, yn);
  }
  // ---- t = 10: window full, first output ----
  {
    float xn[8], yn[8];
    unp(nx[0], xn); unp(ny[0], yn);
    nx[0] = ld8(nrow(xb, 12)); ny[0] = ld8(nrow(yb, 12));
    ox[0] = ld8(orow(xb, 12)); oy[0] = ld8(orow(yb, 12));
    accA(xn, yn);
    emit(10);
  }

  // ---- Phase B: t = 11..25 — full slide + output every step ----
  auto stepB = [&](int t, int s, bool issue) {
    float xn[8], yn[8], xo[8], yo[8];
    unp(nx[s], xn); unp(ny[s], yn); unp(ox[s], xo); unp(oy[s], yo);
    if (issue) {
      nx[s] = ld8(nrow(xb, t + 2)); ny[s] = ld8(nrow(yb, t + 2));
      ox[s] = ld8(orow(xb, t + 2)); oy[s] = ld8(orow(yb, t + 2));
    }
    accB(xn, yn, xo, yo);
    emit(t);
  };

#pragma unroll 1
  for (int u = 0; u < 6; ++u) {        // t = 11..22, slot parity (1,0)
    stepB(11 + 2 * u, 1, true);
    stepB(12 + 2 * u, 0, true);
  }
  stepB(23, 1, true);                  // issues t=25
  stepB(24, 0, false);
  stepB(25, 1, false);
}

extern "C" void kernel_launch(void* const* d_in, const int* in_sizes, int n_in,
                              void* d_out, int out_size, void* d_ws, size_t ws_size,
                              hipStream_t stream)
{
  const float* img = (const float*)d_in[0];
  const float* ref = (const float*)d_in[1];
  const float* drg = (const float*)d_in[2];
  float* out = (float*)d_out;

  // zero dummy row (d_ws is re-poisoned to 0xAA before every launch)
  hipMemsetAsync(d_ws, 0, (size_t)WI * sizeof(float) + 64, stream);

  const int B = in_sizes[0] / (HI * WI);          // 64
  const int waves = B * SPB;                      // 2048
  dim3 grid(waves / 4);                           // 512 blocks, 4 waves each
  dim3 block(256);
  hipLaunchKernelGGL(ssim_wave, grid, block, 0, stream,
                     img, ref, drg, (const float*)d_ws, out);
}